// Round 8
// baseline (426.106 us; speedup 1.0000x reference)
//
#include <hip/hip_runtime.h>
#include <hip/hip_bf16.h>
#include <math.h>

#define Bn 4
#define Tn 1024
#define Cn 1024
#define Hn 16
#define HDn 64
#define FFn 4096

typedef unsigned short ushort_t;
typedef __attribute__((ext_vector_type(8))) short bf16x8;
typedef __attribute__((ext_vector_type(4))) float f32x4;

// round-to-nearest-even float -> bf16 bits
__device__ __forceinline__ ushort_t f2bf(float f) {
  unsigned u = __float_as_uint(f);
  u += 0x7fffu + ((u >> 16) & 1u);
  return (ushort_t)(u >> 16);
}

__device__ __forceinline__ void gload_lds16(const void* g, void* l) {
  __builtin_amdgcn_global_load_lds(
      (const __attribute__((address_space(1))) void*)g,
      (__attribute__((address_space(3))) void*)l, 16, 0, 0);
}

// ---------------------------------------------------------------------------
// LayerNorm: one block (256 threads) per row of C=1024 -> bf16 output.
// ---------------------------------------------------------------------------
__global__ __launch_bounds__(256) void ln_kernel(const float* __restrict__ x,
                                                 const float* __restrict__ g,
                                                 const float* __restrict__ b,
                                                 ushort_t* __restrict__ out) {
  int row = blockIdx.x;
  const float4 v = reinterpret_cast<const float4*>(x + (size_t)row * Cn)[threadIdx.x];
  float s  = v.x + v.y + v.z + v.w;
  float s2 = v.x * v.x + v.y * v.y + v.z * v.z + v.w * v.w;
  for (int m = 1; m < 64; m <<= 1) {
    s  += __shfl_xor(s, m, 64);
    s2 += __shfl_xor(s2, m, 64);
  }
  __shared__ float ls[4], ls2[4];
  int wid = threadIdx.x >> 6;
  if ((threadIdx.x & 63) == 0) { ls[wid] = s; ls2[wid] = s2; }
  __syncthreads();
  s  = ls[0] + ls[1] + ls[2] + ls[3];
  s2 = ls2[0] + ls2[1] + ls2[2] + ls2[3];
  const float mean = s * (1.0f / Cn);
  const float var  = s2 * (1.0f / Cn) - mean * mean;
  const float rstd = rsqrtf(var + 1e-5f);
  const float4 gv = reinterpret_cast<const float4*>(g)[threadIdx.x];
  const float4 bv = reinterpret_cast<const float4*>(b)[threadIdx.x];
  float4 o;
  o.x = (v.x - mean) * rstd * gv.x + bv.x;
  o.y = (v.y - mean) * rstd * gv.y + bv.y;
  o.z = (v.z - mean) * rstd * gv.z + bv.z;
  o.w = (v.w - mean) * rstd * gv.w + bv.w;
  uint2 pk;
  pk.x = (unsigned)f2bf(o.x) | ((unsigned)f2bf(o.y) << 16);
  pk.y = (unsigned)f2bf(o.z) | ((unsigned)f2bf(o.w) << 16);
  reinterpret_cast<uint2*>(out + (size_t)row * Cn)[threadIdx.x] = pk;
}

// ---------------------------------------------------------------------------
// Tiled transpose fp32 [K][N] -> bf16 [N][K]  (coalesced both sides)
// ---------------------------------------------------------------------------
__global__ __launch_bounds__(256) void transpose_f2b(const float* __restrict__ in,
                                                     ushort_t* __restrict__ out,
                                                     int K, int N) {
  __shared__ float t[32][33];
  const int n0 = blockIdx.x * 32, k0 = blockIdx.y * 32;
  const int tx = threadIdx.x & 31, ty = threadIdx.x >> 5;
#pragma unroll
  for (int i = 0; i < 4; ++i)
    t[ty + i * 8][tx] = in[(size_t)(k0 + ty + i * 8) * N + n0 + tx];
  __syncthreads();
#pragma unroll
  for (int i = 0; i < 4; ++i)
    out[(size_t)(n0 + ty + i * 8) * K + k0 + tx] = f2bf(t[tx][ty + i * 8]);
}

// Wq/Wk/Wv [H,C,HD] -> bf16 [3C][C]
__global__ __launch_bounds__(256) void repack_qkv_bf(const float* __restrict__ Wq,
                                                     const float* __restrict__ Wk,
                                                     const float* __restrict__ Wv,
                                                     ushort_t* __restrict__ out) {
  __shared__ float t[32][33];
  const int z = blockIdx.z;
  const int ti = z >> 4, h = z & 15;
  const float* in = (ti == 0 ? Wq : (ti == 1 ? Wk : Wv)) + (size_t)h * Cn * HDn;
  ushort_t* o = out + (size_t)(ti * Cn + h * HDn) * Cn;
  const int n0 = blockIdx.x * 32, k0 = blockIdx.y * 32;
  const int tx = threadIdx.x & 31, ty = threadIdx.x >> 5;
#pragma unroll
  for (int i = 0; i < 4; ++i)
    t[ty + i * 8][tx] = in[(size_t)(k0 + ty + i * 8) * HDn + n0 + tx];
  __syncthreads();
#pragma unroll
  for (int i = 0; i < 4; ++i)
    o[(size_t)(n0 + ty + i * 8) * Cn + k0 + tx] = f2bf(t[tx][ty + i * 8]);
}

// V columns of bf16 qkv [B*T][3C] -> vT [B*H][HD][T]
__global__ __launch_bounds__(256) void vtrans(const ushort_t* __restrict__ qkv,
                                              ushort_t* __restrict__ vT) {
  __shared__ ushort_t t[32][34];
  const int t0 = blockIdx.x * 32;
  const int d0 = blockIdx.y * 32;
  const int bh = blockIdx.z;
  const int b = bh >> 4, h = bh & 15;
  const int tx = threadIdx.x & 31, ty = threadIdx.x >> 5;
#pragma unroll
  for (int i = 0; i < 4; ++i)
    t[ty + i * 8][tx] = qkv[(size_t)(b * Tn + t0 + ty + i * 8) * (3 * Cn) +
                            2 * Cn + h * HDn + d0 + tx];
  __syncthreads();
#pragma unroll
  for (int i = 0; i < 4; ++i)
    vT[(size_t)(bh * HDn + d0 + ty + i * 8) * Tn + t0 + tx] = t[tx][ty + i * 8];
}

// ---------------------------------------------------------------------------
// bf16 MFMA GEMM, depth-2 pipelined (T3+T4 minimum):
//   C = ep(A[MxK] @ Bt[NxK]^T + bias) + res
// 3 LDS buffers; counted s_waitcnt vmcnt(L) (never 0 in steady state) + raw
// s_barrier; stage(t+2) issued right after the barrier. LDS granule swizzle
// granule ^= (row>>1)&3, realized as pre-swizzled per-lane GLOBAL source
// (linear global_load_lds dest) + matching XOR on ds_read side.
// BM=128: 4 waves 2x2 (64x64 each), 4 loads/wave/tile -> vmcnt(4).
// BM=64:  4 waves 1x4 (64x32 each), 3 loads/wave/tile -> vmcnt(3).
// ---------------------------------------------------------------------------
template <int BM>
__global__ __launch_bounds__(256) void gemm_bt(const ushort_t* __restrict__ A,
                                               const ushort_t* __restrict__ Bt,
                                               const float* __restrict__ bias,
                                               const float* __restrict__ res,
                                               float* __restrict__ Cf,
                                               ushort_t* __restrict__ Cb,
                                               int M, int N, int K, int act) {
  constexpr int FN = (BM == 128) ? 4 : 2;
  __shared__ ushort_t As[3][BM * 32];
  __shared__ ushort_t Bs[3][128 * 32];
  const int tid = threadIdx.x;
  const int w = tid >> 6, lane = tid & 63;
  const int n0 = blockIdx.x * 128, m0 = blockIdx.y * BM;
  const int woffM = (BM == 128) ? (w >> 1) * 64 : 0;
  const int woffN = (BM == 128) ? (w & 1) * 64 : w * 32;
  const int lr = lane & 15, lg = lane >> 4;

  f32x4 acc[4][FN];
  const f32x4 zero = {0.f, 0.f, 0.f, 0.f};
#pragma unroll
  for (int i = 0; i < 4; ++i)
#pragma unroll
    for (int j = 0; j < FN; ++j) acc[i][j] = zero;

  // staging: lane covers (row = lane>>2, granule = lane&3); global granule
  // pre-swizzled so that linear LDS writes realize lds(r,g)=global(r, g^((r>>1)&3))
  const int srow = lane >> 2;                                   // 0..15
  const int skc  = ((lane & 3) ^ ((lane >> 3) & 3)) * 8;        // swizzled k offset
  const int arow0 = (BM == 128) ? (w * 32) : (w * 16);
  const ushort_t* Ag = A  + (size_t)(m0 + arow0 + srow) * K + skc;
  const ushort_t* Bg = Bt + (size_t)(n0 + w * 32 + srow) * K + skc;

  const int NT = K >> 5;

  auto stage = [&](int buf, int tt) {
    const int k0 = tt << 5;
    gload_lds16(Ag + k0, &As[buf][arow0 * 32]);
    if constexpr (BM == 128)
      gload_lds16(Ag + (size_t)16 * K + k0, &As[buf][(arow0 + 16) * 32]);
    gload_lds16(Bg + k0, &Bs[buf][(w * 32) * 32]);
    gload_lds16(Bg + (size_t)16 * K + k0, &Bs[buf][(w * 32 + 16) * 32]);
  };

  stage(0, 0);
  stage(1, 1);

  int b0 = 0, b1 = 1, b2 = 2;
  // read-side swizzled granule offsets (elements)
  const int gA = (lg ^ ((lr >> 1) & 3)) * 8;

  for (int t = 0; t < NT; ++t) {
    if (t + 1 < NT) {
      if constexpr (BM == 128) asm volatile("s_waitcnt vmcnt(4)" ::: "memory");
      else                     asm volatile("s_waitcnt vmcnt(3)" ::: "memory");
    } else {
      asm volatile("s_waitcnt vmcnt(0)" ::: "memory");
    }
    __builtin_amdgcn_sched_barrier(0);
    __builtin_amdgcn_s_barrier();
    __builtin_amdgcn_sched_barrier(0);
    if (t + 2 < NT) stage(b2, t + 2);

    bf16x8 af[4], bfr[FN];
#pragma unroll
    for (int m = 0; m < 4; ++m)
      af[m] = *reinterpret_cast<const bf16x8*>(
          &As[b0][(woffM + m * 16 + lr) * 32 + gA]);
#pragma unroll
    for (int n = 0; n < FN; ++n)
      bfr[n] = *reinterpret_cast<const bf16x8*>(
          &Bs[b0][(woffN + n * 16 + lr) * 32 + gA]);
#pragma unroll
    for (int m = 0; m < 4; ++m)
#pragma unroll
      for (int n = 0; n < FN; ++n)
        acc[m][n] = __builtin_amdgcn_mfma_f32_16x16x32_bf16(af[m], bfr[n], acc[m][n], 0, 0, 0);

    const int tmp = b0; b0 = b1; b1 = b2; b2 = tmp;
  }

  // epilogue: C/D layout col=lane&15, row=(lane>>4)*4+reg
#pragma unroll
  for (int m = 0; m < 4; ++m) {
    const int rowb = m0 + woffM + m * 16 + lg * 4;
#pragma unroll
    for (int n = 0; n < FN; ++n) {
      const int col = n0 + woffN + n * 16 + lr;
      const float bb = bias ? bias[col] : 0.0f;
      f32x4 v = acc[m][n];
#pragma unroll
      for (int r = 0; r < 4; ++r) {
        float y = v[r] + bb;
        if (act == 1) y = 0.5f * y * (1.0f + erff(y * 0.70710678118654752f));
        if (res) y += res[(size_t)(rowb + r) * N + col];
        if (Cb) Cb[(size_t)(rowb + r) * N + col] = f2bf(y);
        else    Cf[(size_t)(rowb + r) * N + col] = y;
      }
    }
  }
}

// ---------------------------------------------------------------------------
// MFMA flash attention. Block = (q-tile 64, h, b); 4 waves x 16 q-rows.
// qkv bf16 [B*T][3C]; vT bf16 [B*H][HD][T]; out bf16 [B*T][C].
// LDS tiles [64][64] bf16, XOR-swizzled: elem ^= (row&7)<<3.
// ---------------------------------------------------------------------------
__global__ __launch_bounds__(256) void attn_mfma(const ushort_t* __restrict__ qkv,
                                                 const ushort_t* __restrict__ vT,
                                                 ushort_t* __restrict__ out) {
  const int qt = blockIdx.x, h = blockIdx.y, b = blockIdx.z;
  const int tid = threadIdx.x;
  const int w = tid >> 6;
  const int lane = tid & 63;
  const int lr = lane & 15, lg = lane >> 4;
  const int q0 = qt * 64;
  const int bh = b * Hn + h;

  __shared__ ushort_t Ks[64 * 64];
  __shared__ ushort_t Vts[64 * 64];
  __shared__ ushort_t Ps[64 * 64];

  bf16x8 qf[2];
  {
    const ushort_t* qp = qkv + (size_t)(b * Tn + q0 + w * 16 + lr) * (3 * Cn) + h * HDn;
    qf[0] = *reinterpret_cast<const bf16x8*>(qp + lg * 8);
    qf[1] = *reinterpret_cast<const bf16x8*>(qp + 32 + lg * 8);
  }

  f32x4 acc[4];
  const f32x4 fzero = {0.f, 0.f, 0.f, 0.f};
  acc[0] = acc[1] = acc[2] = acc[3] = fzero;
  float m_[4] = {-1e30f, -1e30f, -1e30f, -1e30f};
  float l_[4] = {0.f, 0.f, 0.f, 0.f};

  const int srow = tid >> 3;       // 0..31
  const int sc   = (tid & 7) * 8;  // element offset (16B granule)

  for (int kt = 0; kt <= qt; ++kt) {
    const int s0 = kt * 64;
#pragma unroll
    for (int p = 0; p < 2; ++p) {
      const int row = srow + p * 32;
      const uint4 kv = *reinterpret_cast<const uint4*>(
          qkv + (size_t)(b * Tn + s0 + row) * (3 * Cn) + Cn + h * HDn + sc);
      *reinterpret_cast<uint4*>(&Ks[row * 64 + (sc ^ ((row & 7) << 3))]) = kv;
      const uint4 vv = *reinterpret_cast<const uint4*>(
          vT + (size_t)(bh * HDn + row) * Tn + s0 + sc);
      *reinterpret_cast<uint4*>(&Vts[row * 64 + (sc ^ ((row & 7) << 3))]) = vv;
    }
    __syncthreads();

    f32x4 sf[4];
    sf[0] = sf[1] = sf[2] = sf[3] = fzero;
#pragma unroll
    for (int n = 0; n < 4; ++n) {
      const int krow = n * 16 + lr;
#pragma unroll
      for (int c = 0; c < 2; ++c) {
        const bf16x8 kf = *reinterpret_cast<const bf16x8*>(
            &Ks[krow * 64 + ((c * 32 + lg * 8) ^ ((krow & 7) << 3))]);
        sf[n] = __builtin_amdgcn_mfma_f32_16x16x32_bf16(qf[c], kf, sf[n], 0, 0, 0);
      }
    }

    const bool diag = (kt == qt);
#pragma unroll
    for (int r = 0; r < 4; ++r) {
      const int qg = q0 + w * 16 + lg * 4 + r;
      float mx = -1e30f;
#pragma unroll
      for (int n = 0; n < 4; ++n) {
        float s = sf[n][r] * 0.125f;
        if (diag && (s0 + n * 16 + lr) > qg) s = -1e30f;
        sf[n][r] = s;
        mx = fmaxf(mx, s);
      }
      mx = fmaxf(mx, __shfl_xor(mx, 1));
      mx = fmaxf(mx, __shfl_xor(mx, 2));
      mx = fmaxf(mx, __shfl_xor(mx, 4));
      mx = fmaxf(mx, __shfl_xor(mx, 8));
      const float mn = fmaxf(m_[r], mx);
      const float sfac = __expf(m_[r] - mn);
      m_[r] = mn;
      float ls = 0.f;
#pragma unroll
      for (int n = 0; n < 4; ++n) {
        const float p = __expf(sf[n][r] - mn);
        sf[n][r] = p;
        ls += p;
      }
      ls += __shfl_xor(ls, 1);
      ls += __shfl_xor(ls, 2);
      ls += __shfl_xor(ls, 4);
      ls += __shfl_xor(ls, 8);
      l_[r] = l_[r] * sfac + ls;
#pragma unroll
      for (int n = 0; n < 4; ++n) acc[n][r] *= sfac;
      const int prow = w * 16 + lg * 4 + r;
#pragma unroll
      for (int n = 0; n < 4; ++n)
        Ps[prow * 64 + ((n * 16 + lr) ^ ((prow & 7) << 3))] = f2bf(sf[n][r]);
    }

#pragma unroll
    for (int sb = 0; sb < 2; ++sb) {
      const int prow = w * 16 + lr;
      const bf16x8 pf = *reinterpret_cast<const bf16x8*>(
          &Ps[prow * 64 + ((sb * 32 + lg * 8) ^ ((prow & 7) << 3))]);
#pragma unroll
      for (int nf = 0; nf < 4; ++nf) {
        const int vrow = nf * 16 + lr;
        const bf16x8 vf = *reinterpret_cast<const bf16x8*>(
            &Vts[vrow * 64 + ((sb * 32 + lg * 8) ^ ((vrow & 7) << 3))]);
        acc[nf] = __builtin_amdgcn_mfma_f32_16x16x32_bf16(pf, vf, acc[nf], 0, 0, 0);
      }
    }
    __syncthreads();
  }

#pragma unroll
  for (int r = 0; r < 4; ++r) {
    const float inv = 1.0f / l_[r];
    const int qg = q0 + w * 16 + lg * 4 + r;
#pragma unroll
    for (int nf = 0; nf < 4; ++nf)
      out[(size_t)(b * Tn + qg) * Cn + h * HDn + nf * 16 + lr] = f2bf(acc[nf][r] * inv);
  }
}

// ---------------------------------------------------------------------------
// Launch
// ---------------------------------------------------------------------------
extern "C" void kernel_launch(void* const* d_in, const int* in_sizes, int n_in,
                              void* d_out, int out_size, void* d_ws, size_t ws_size,
                              hipStream_t stream) {
  const float* x      = (const float*)d_in[0];
  const float* ln1_g  = (const float*)d_in[1];
  const float* ln1_b  = (const float*)d_in[2];
  const float* ln2_g  = (const float*)d_in[3];
  const float* ln2_b  = (const float*)d_in[4];
  const float* Wq     = (const float*)d_in[5];
  const float* Wk     = (const float*)d_in[6];
  const float* Wv     = (const float*)d_in[7];
  const float* Wproj  = (const float*)d_in[8];
  const float* bproj  = (const float*)d_in[9];
  const float* W1     = (const float*)d_in[10];
  const float* b1     = (const float*)d_in[11];
  const float* W2     = (const float*)d_in[12];
  const float* b2     = (const float*)d_in[13];
  float* out = (float*)d_out;

  char* wsb = (char*)d_ws;
  ushort_t* xn_bf   = (ushort_t*)(wsb);                        // 8MB
  ushort_t* attn_bf = (ushort_t*)(wsb + ((size_t)8  << 20));   // 8MB
  float*    x2      = (float*)  (wsb + ((size_t)16 << 20));    // 16MB
  ushort_t* qkv_bf  = (ushort_t*)(wsb + ((size_t)32 << 20));   // 24MB [4096][3072]
  ushort_t* vTb     = (ushort_t*)(wsb + ((size_t)56 << 20));   // 8MB  [64][64][1024]
  ushort_t* hbuf    = (ushort_t*)(wsb + ((size_t)32 << 20));   // 32MB (reuses qkv+vT)
  ushort_t* wqkv_t  = (ushort_t*)(wsb + ((size_t)64 << 20));   // 6MB
  ushort_t* wproj_t = (ushort_t*)(wsb + ((size_t)70 << 20));   // 2MB
  ushort_t* w1_t    = (ushort_t*)(wsb + ((size_t)72 << 20));   // 8MB
  ushort_t* w2_t    = (ushort_t*)(wsb + ((size_t)80 << 20));   // 8MB

  const int Mrows = Bn * Tn;  // 4096

  // weight repacks (bf16, [N][K])
  repack_qkv_bf<<<dim3(2, 32, 48), 256, 0, stream>>>(Wq, Wk, Wv, wqkv_t);
  transpose_f2b<<<dim3(Cn / 32, Cn / 32), 256, 0, stream>>>(Wproj, wproj_t, Cn, Cn);
  transpose_f2b<<<dim3(FFn / 32, Cn / 32), 256, 0, stream>>>(W1, w1_t, Cn, FFn);
  transpose_f2b<<<dim3(Cn / 32, FFn / 32), 256, 0, stream>>>(W2, w2_t, FFn, Cn);

  // 1. LN1 -> bf16
  ln_kernel<<<Mrows, 256, 0, stream>>>(x, ln1_g, ln1_b, xn_bf);

  // 2. QKV = xn @ Wqkv -> bf16 [4096 x 3072]   (768 blocks, 3/CU)
  gemm_bt<128><<<dim3(3 * Cn / 128, Mrows / 128), 256, 0, stream>>>(
      xn_bf, wqkv_t, nullptr, nullptr, nullptr, qkv_bf, Mrows, 3 * Cn, Cn, 0);

  // 2b. V^T for attention
  vtrans<<<dim3(Tn / 32, HDn / 32, Bn * Hn), 256, 0, stream>>>(qkv_bf, vTb);

  // 3. MFMA flash attention -> bf16 [4096 x 1024]
  attn_mfma<<<dim3(Tn / 64, Hn, Bn), 256, 0, stream>>>(qkv_bf, vTb, attn_bf);

  // 4. x2 = x + attn @ Wproj + bproj  (fp32)   (BM=64: 512 blocks, 2/CU)
  gemm_bt<64><<<dim3(Cn / 128, Mrows / 64), 256, 0, stream>>>(
      attn_bf, wproj_t, bproj, x, x2, nullptr, Mrows, Cn, Cn, 0);

  // 5. LN2 -> bf16
  ln_kernel<<<Mrows, 256, 0, stream>>>(x2, ln2_g, ln2_b, xn_bf);

  // 6. h = gelu(xn @ W1 + b1) -> bf16 [4096 x 4096]   (1024 blocks)
  gemm_bt<128><<<dim3(FFn / 128, Mrows / 128), 256, 0, stream>>>(
      xn_bf, w1_t, b1, nullptr, nullptr, hbuf, Mrows, FFn, Cn, 1);

  // 7. out = x2 + h @ W2 + b2  (fp32)   (BM=64: 512 blocks, 2/CU)
  gemm_bt<64><<<dim3(Cn / 128, Mrows / 64), 256, 0, stream>>>(
      hbuf, w2_t, b2, x2, out, nullptr, Mrows, Cn, FFn, 0);
}